// Round 10
// baseline (551.735 us; speedup 1.0000x reference)
//
#include <hip/hip_runtime.h>

// FWLNet pipeline; see R5-R9 notes.
//
// R10 (from R9 pass @520.6us): k_buildT ONLY (single-variable):
//  - Wt B-fragments hoisted to registers (jc-invariant; kills 16 b128
//    LDS reads/chunk = 256/block).
//  - Wt LDS packed to stride 128 and ALIASED with scratch (Wt is dead after
//    the one-time register read) -> LDS 43.5 -> 33.7 KB.
//  - __launch_bounds__(256,4): 4 blocks/CU (was 3); latency-bound kernel.
//
// ws layout unchanged (~194.4 MB).

typedef unsigned short u16;
typedef unsigned int u32;

#define DI static __device__ __forceinline__

DI float bf2f(u16 u) { union { u32 i; float f; } v; v.i = ((u32)u) << 16; return v.f; }
DI u16 f2bf(float f) {
  union { float f; u32 i; } v; v.f = f;
  u32 u = v.i;
  return (u16)((u + 0x7fffu + ((u >> 16) & 1u)) >> 16);
}

typedef __bf16 bf16x8 __attribute__((ext_vector_type(8)));
typedef float f32x4 __attribute__((ext_vector_type(4)));

#define MFMA16(a, b, c) __builtin_amdgcn_mfma_f32_16x16x32_bf16((a), (b), (c), 0, 0, 0)

typedef const __attribute__((address_space(1))) u32* gas1;
typedef __attribute__((address_space(3))) u32* las3;

// ---------------- node pipeline ----------------

__global__ void k_setup(const int* __restrict__ xids, const float* __restrict__ emb,
                        float* __restrict__ xf, float* __restrict__ deg,
                        u32* __restrict__ eimu) {
  int g = blockIdx.x * 256 + threadIdx.x;  // grid 1024
  if (g < 262144) eimu[g] = 0u;
  if (g < 1024) deg[g] = 1.0f;  // self-loop
  if (g < 65536) {
    int i = g >> 6, d = g & 63;
    xf[g] = emb[xids[i] * 64 + d];
  }
}

__global__ void k_edges(const int* __restrict__ ei, float* __restrict__ deg,
                        unsigned char* __restrict__ eim) {
  int e = blockIdx.x * 256 + threadIdx.x;  // grid 64
  if (e < 16384) {
    int s = ei[e], d = ei[16384 + e];
    atomicAdd(&deg[d], 1.0f);
    eim[s * 1024 + d] = 1;
  }
}

__global__ void k_gemm_node(const float* __restrict__ xf, const float* __restrict__ W,
                            const float* __restrict__ gb, const float* __restrict__ deg,
                            float* __restrict__ h, float* __restrict__ agg) {
  __shared__ float xrow[64];
  int i = blockIdx.x, c = threadIdx.x;  // grid 1024 x 64
  xrow[c] = xf[i * 64 + c];
  __syncthreads();
  float s = 0.f;
#pragma unroll
  for (int d = 0; d < 64; ++d) s += xrow[d] * W[d * 64 + c];
  h[i * 64 + c] = s;
  agg[i * 64 + c] = s / deg[i] + gb[c];
}

__global__ void k_agg(const int* __restrict__ ei, const float* __restrict__ deg,
                      const float* __restrict__ h, float* __restrict__ agg) {
  int g = blockIdx.x * 256 + threadIdx.x;  // grid 4096 -> e x c
  int e = g >> 6, c = g & 63;
  int s = ei[e], d = ei[16384 + e];
  float nrm = rsqrtf(deg[s]) * rsqrtf(deg[d]);
  atomicAdd(&agg[d * 64 + c], nrm * h[s * 64 + c]);
}

__global__ void k_gnorm(const float* __restrict__ agg, const float* __restrict__ gw,
                        const float* __restrict__ gbb, const float* __restrict__ ga,
                        float* __restrict__ xf, u16* __restrict__ xb, int last) {
  int c = blockIdx.x, t = threadIdx.x;  // grid 64 x 256
  float s = 0.f, ss = 0.f;
  for (int i = t; i < 1024; i += 256) {
    float v = agg[i * 64 + c];
    s += v; ss += v * v;
  }
  __shared__ float Ls[256], Lss[256];
  Ls[t] = s; Lss[t] = ss;
  __syncthreads();
  for (int off = 128; off > 0; off >>= 1) {
    if (t < off) { Ls[t] += Ls[t + off]; Lss[t] += Lss[t + off]; }
    __syncthreads();
  }
  float m = Ls[0] * (1.f / 1024.f);
  float a = ga[c];
  float var = Lss[0] * (1.f / 1024.f) - (2.f * a - a * a) * m * m;
  float sc = gw[c] * rsqrtf(fmaxf(var, 0.f) + 1e-5f);
  float bb = gbb[c];
  for (int i = t; i < 1024; i += 256) {
    float v = agg[i * 64 + c];
    float y = fmaxf(sc * (v - a * m) + bb, 0.f);
    xf[i * 64 + c] = y;
    if (last) xb[i * 64 + c] = f2bf(y);
  }
}

// ---------------- x1t / x2T builder: 4 channels per block ----------------
__global__ __launch_bounds__(256, 2) void k_build12(
    const u16* __restrict__ xbg, const unsigned char* __restrict__ eim,
    const float* __restrict__ m1W, const float* __restrict__ m1b,
    const float* __restrict__ m2W, const float* __restrict__ m2b,
    u16* __restrict__ x1tg, u16* __restrict__ x2tg, int cbase) {
  __shared__ u16 As[128 * 80];
  __shared__ u16 Bs[128 * 80];
  __shared__ u16 Cs[64 * 140];
  __shared__ unsigned char El[128 * 132];
  __shared__ float wsc[64];
  int b = blockIdx.x;  // grid 512 = 2(which) x 64 tiles x 4 channel-quads
  int cg = b & 3;
  int rest = b >> 2;
  int which = rest >> 6;
  int t6 = rest & 63;
  int rbase = (t6 >> 3) * 128, sbase = (t6 & 7) * 128;
  const float* W = which ? m2W : m1W;
  const float* bias = which ? m2b : m1b;
  u16* outg = which ? x2tg : x1tg;
  int t = threadIdx.x;
  {
    int row = t >> 1, half = t & 1;
    const u32* gB = (const u32*)(xbg + (sbase + row) * 64 + half * 32);
    u32* dstB = (u32*)&Bs[row * 80 + half * 32];
#pragma unroll
    for (int k = 0; k < 16; ++k) dstB[k] = gB[k];
    int ab = which ? sbase : rbase;
    int bb = which ? rbase : sbase;
    const u32* gE = (const u32*)(eim + (size_t)(ab + row) * 1024 + bb + half * 64);
    u32* dstE = (u32*)&El[row * 132 + half * 64];
#pragma unroll
    for (int k = 0; k < 16; ++k) dstE[k] = gE[k];
  }
  int lane = t & 63, w = t >> 6;
  int q = lane >> 4, r = lane & 15;
  int wr = w >> 1, wc = w & 1;
  for (int ci = 0; ci < 4; ++ci) {
    int cl = cg * 4 + ci;
    int c = cbase + cl;
    if (t < 64) wsc[t] = W[t * 64 + c];
    __syncthreads();
    {
      int row = t >> 1, half = t & 1;
      const u32* ga = (const u32*)(xbg + (rbase + row) * 64 + half * 32);
      u32* dstA = (u32*)&As[row * 80 + half * 32];
#pragma unroll
      for (int k = 0; k < 16; ++k) {
        u32 u = ga[k];
        float f0 = bf2f((u16)(u & 0xffffu)) * wsc[half * 32 + 2 * k];
        float f1 = bf2f((u16)(u >> 16)) * wsc[half * 32 + 2 * k + 1];
        dstA[k] = (u32)f2bf(f0) | ((u32)f2bf(f1) << 16);
      }
    }
    __syncthreads();
    f32x4 z4 = {0.f, 0.f, 0.f, 0.f};
    f32x4 acc[4][4];
#pragma unroll
    for (int mi = 0; mi < 4; ++mi)
#pragma unroll
      for (int ni = 0; ni < 4; ++ni) acc[mi][ni] = z4;
#pragma unroll
    for (int ks = 0; ks < 2; ++ks) {
      bf16x8 af[4], bfr[4];
#pragma unroll
      for (int mi = 0; mi < 4; ++mi)
        af[mi] = *(const bf16x8*)&As[(wr * 64 + mi * 16 + r) * 80 + ks * 32 + q * 8];
#pragma unroll
      for (int ni = 0; ni < 4; ++ni)
        bfr[ni] = *(const bf16x8*)&Bs[(wc * 64 + ni * 16 + r) * 80 + ks * 32 + q * 8];
#pragma unroll
      for (int mi = 0; mi < 4; ++mi)
#pragma unroll
        for (int ni = 0; ni < 4; ++ni) acc[mi][ni] = MFMA16(af[mi], bfr[ni], acc[mi][ni]);
    }
    float w64 = W[64 * 64 + c];
    float bsv = bias[c];
#pragma unroll
    for (int mi = 0; mi < 4; ++mi) {
#pragma unroll
      for (int ni = 0; ni < 4; ++ni) {
        int col = wc * 64 + ni * 16 + r;
#pragma unroll
        for (int tt = 0; tt < 4; ++tt) {
          int row2 = wr * 64 + mi * 16 + q * 4 + tt;
          float e = (float)(which ? El[col * 132 + row2] : El[row2 * 132 + col]);
          acc[mi][ni][tt] = fmaxf(acc[mi][ni][tt] + e * w64 + bsv, 0.f);
        }
      }
    }
    u16* outp = outg + (size_t)cl * 1048576;
#pragma unroll
    for (int p = 0; p < 2; ++p) {
      __syncthreads();
      if (wr == p) {
#pragma unroll
        for (int mi = 0; mi < 4; ++mi)
#pragma unroll
          for (int ni = 0; ni < 4; ++ni) {
            int col = wc * 64 + ni * 16 + r;
#pragma unroll
            for (int tt = 0; tt < 4; ++tt) {
              int lrow = mi * 16 + q * 4 + tt;
              Cs[lrow * 140 + col] = f2bf(acc[mi][ni][tt]);
            }
          }
      }
      __syncthreads();
      {
        int rl = t >> 4, ch = t & 15;
#pragma unroll
        for (int it = 0; it < 4; ++it) {
          int row = it * 16 + rl;
          uint4 v = *(const uint4*)&Cs[row * 140 + ch * 8];
          *(uint4*)(outp + (size_t)(rbase + p * 64 + row) * 1024 + sbase + ch * 8) = v;
        }
      }
    }
  }
}

// ---------------- batched prod GEMM (16 channels per launch) ----------------
__global__ __launch_bounds__(256, 4) void k_prodgemm(
    const u16* __restrict__ x1tg, const u16* __restrict__ x2tg,
    u16* __restrict__ prod, int cbase) {
  __shared__ u16 pool[17408];
  int b = blockIdx.x;  // grid 1024 = 64 tiles x 16 ch (cl low bits)
  int cl = b & 15;
  int tile = b >> 4;
  int i0 = (tile >> 3) * 128, j0 = (tile & 7) * 128;
  const u16* Ap = x1tg + (size_t)cl * 1048576;
  const u16* Bp = x2tg + (size_t)cl * 1048576;
  u16* Pp = prod + (size_t)(cbase + cl) * 1048576;
  int t = threadIdx.x, lane = t & 63, w = t >> 6;
  int q = lane >> 4, r = lane & 15;
  int wr = w >> 1, wc = w & 1;
  int lrow = lane >> 3, lcol = (lane & 7) * 8;
  f32x4 z4 = {0.f, 0.f, 0.f, 0.f};
  f32x4 acc[4][4];
#pragma unroll
  for (int mi = 0; mi < 4; ++mi)
#pragma unroll
    for (int ni = 0; ni < 4; ++ni) acc[mi][ni] = z4;
  for (int kk = 0; kk < 1024; kk += 64) {
    __syncthreads();
#pragma unroll
    for (int s8 = 0; s8 < 4; ++s8) {
      int rowbase = w * 32 + s8 * 8;
      int grow = rowbase + lrow;
      __builtin_amdgcn_global_load_lds(
          (gas1)(Ap + (size_t)(i0 + grow) * 1024 + kk + lcol),
          (las3)&pool[rowbase * 64], 16, 0, 0);
      __builtin_amdgcn_global_load_lds(
          (gas1)(Bp + (size_t)(j0 + grow) * 1024 + kk + lcol),
          (las3)&pool[8192 + rowbase * 64], 16, 0, 0);
    }
    __syncthreads();
#pragma unroll
    for (int ks = 0; ks < 2; ++ks) {
      bf16x8 af[4], bfr[4];
#pragma unroll
      for (int mi = 0; mi < 4; ++mi)
        af[mi] = *(const bf16x8*)&pool[(wr * 64 + mi * 16 + r) * 64 + ks * 32 + q * 8];
#pragma unroll
      for (int ni = 0; ni < 4; ++ni)
        bfr[ni] = *(const bf16x8*)&pool[8192 + (wc * 64 + ni * 16 + r) * 64 + ks * 32 + q * 8];
#pragma unroll
      for (int mi = 0; mi < 4; ++mi)
#pragma unroll
        for (int ni = 0; ni < 4; ++ni) acc[mi][ni] = MFMA16(af[mi], bfr[ni], acc[mi][ni]);
    }
  }
  __syncthreads();
#pragma unroll
  for (int mi = 0; mi < 4; ++mi)
#pragma unroll
    for (int ni = 0; ni < 4; ++ni) {
      int col = wc * 64 + ni * 16 + r;
#pragma unroll
      for (int tt = 0; tt < 4; ++tt) {
        int row2 = wr * 64 + mi * 16 + q * 4 + tt;
        pool[row2 * 136 + col] = f2bf(acc[mi][ni][tt]);
      }
    }
  __syncthreads();
  {
    int rseg = t >> 4, cseg = t & 15;
#pragma unroll
    for (int it = 0; it < 8; ++it) {
      int row = it * 16 + rseg;
      uint4 v = *(const uint4*)&pool[row * 136 + cseg * 8];
      *(uint4*)(Pp + (size_t)(i0 + row) * 1024 + j0 + cseg * 8) = v;
    }
  }
}

// ---------------- T = [x_i*x_j | eim | prod] @ m3W + b3 (IN PLACE over prod) --
// R10: Wt fragments in registers (loaded once from packed-LDS Wt); Wt LDS
// region reused as scratch afterwards. LDS 33.7KB -> 4 blocks/CU.
__global__ __launch_bounds__(256, 4) void k_buildT(
    const u16* __restrict__ xbg, const unsigned char* __restrict__ eim,
    u16* PT, const float* __restrict__ m3W, const float* __restrict__ m3b,
    float* __restrict__ S, float* __restrict__ SS) {
  __shared__ u16 A[64 * 136];     // [j][k]: k<64 x-part, k>=64 prod-part; Cs alias
  __shared__ u16 WtS[64 * 128];   // phase 1: packed Wt[c][k]; phase 2: scratch
  __shared__ float xi[64];
  u16* scratch = WtS;             // [plane][64j + 2 pad] stride 66, fits 8448<=8192? no: 64*66=4224 u16 <= 8192 OK
  int i = blockIdx.x;  // grid 1024
  int t = threadIdx.x, lane = t & 63, w = t >> 6;
  int q = lane >> 4, r = lane & 15;
  {
    int zidx = i * 256 + t;
    if (zidx < 65536) { S[zidx] = 0.f; SS[zidx] = 0.f; }
  }
  if (t < 64) xi[t] = bf2f(xbg[i * 64 + t]);
  {
    int row = t >> 1, half = t & 1;
    int rsrc = row < 64 ? row : row + 1;  // skip eim row 64
    const float4* gw = (const float4*)(m3W + rsrc * 64 + half * 32);
#pragma unroll
    for (int k = 0; k < 8; ++k) {
      float4 f = gw[k];
      WtS[(half * 32 + 4 * k + 0) * 128 + row] = f2bf(f.x);
      WtS[(half * 32 + 4 * k + 1) * 128 + row] = f2bf(f.y);
      WtS[(half * 32 + 4 * k + 2) * 128 + row] = f2bf(f.z);
      WtS[(half * 32 + 4 * k + 3) * 128 + row] = f2bf(f.w);
    }
  }
  float w64c[4], b3c[4];
#pragma unroll
  for (int ni = 0; ni < 4; ++ni) {
    int cc = ni * 16 + r;
    w64c[ni] = m3W[64 * 64 + cc];
    b3c[ni] = m3b[cc];
  }
  __syncthreads();  // Wt staged
  // one-time register hoist of all B fragments (jc-invariant)
  bf16x8 bfrr[4][4];
#pragma unroll
  for (int ks = 0; ks < 4; ++ks)
#pragma unroll
    for (int ni = 0; ni < 4; ++ni)
      bfrr[ks][ni] = *(const bf16x8*)&WtS[(ni * 16 + r) * 128 + ks * 32 + q * 8];
  for (int jc = 0; jc < 16; ++jc) {
    int j0 = jc * 64;
    __syncthreads();  // prior A/scratch reads done; (jc=0) guards bfrr reads vs scratch writes
    {
      // x-part: A[jj][0..63] = x[j0+jj,:] * x[i,:]  (4 threads/row, 16 cols)
      int jj = t >> 2, quar = t & 3;
      const u32* gx = (const u32*)(xbg + (j0 + jj) * 64 + quar * 16);
      u32* dst = (u32*)&A[jj * 136 + quar * 16];
#pragma unroll
      for (int k = 0; k < 8; ++k) {
        u32 u = gx[k];
        float f0 = bf2f((u16)(u & 0xffffu)) * xi[quar * 16 + 2 * k];
        float f1 = bf2f((u16)(u >> 16)) * xi[quar * 16 + 2 * k + 1];
        dst[k] = (u32)f2bf(f0) | ((u32)f2bf(f1) << 16);
      }
      // prod stage 1: coalesced global -> scratch (4 lanes/plane, 32B each)
      int p = t >> 2, pt = t & 3;
      const uint4* gp = (const uint4*)(PT + (size_t)p * 1048576 + (size_t)i * 1024 + j0 + pt * 16);
      uint4 v0 = gp[0];
      uint2 v1 = ((const uint2*)gp)[2];
      uint2 v2 = ((const uint2*)gp)[3];
      u32* sw = (u32*)&scratch[p * 66 + pt * 16];
      sw[0] = v0.x; sw[1] = v0.y; sw[2] = v0.z; sw[3] = v0.w;
      sw[4] = v1.x; sw[5] = v1.y; sw[6] = v2.x; sw[7] = v2.y;
    }
    __syncthreads();
    {
      // prod stage 2: scratch -> A transpose (row stride 66 -> 2-way free)
#pragma unroll
      for (int jj2 = 0; jj2 < 8; ++jj2) {
        int jr = w * 16 + jj2 * 2;
        u32 two = *(const u32*)&scratch[lane * 66 + jr];
        A[jr * 136 + 64 + lane] = (u16)(two & 0xffffu);
        A[(jr + 1) * 136 + 64 + lane] = (u16)(two >> 16);
      }
    }
    __syncthreads();
    f32x4 z4 = {0.f, 0.f, 0.f, 0.f};
    f32x4 acc[4];
#pragma unroll
    for (int ni = 0; ni < 4; ++ni) acc[ni] = z4;
#pragma unroll
    for (int ks = 0; ks < 4; ++ks) {
      bf16x8 af = *(const bf16x8*)&A[(w * 16 + r) * 136 + ks * 32 + q * 8];
#pragma unroll
      for (int ni = 0; ni < 4; ++ni) acc[ni] = MFMA16(af, bfrr[ks][ni], acc[ni]);
    }
#pragma unroll
    for (int tt = 0; tt < 4; ++tt) {
      int jj = w * 16 + q * 4 + tt;
      float ev = (float)eim[(size_t)i * 1024 + j0 + jj];
#pragma unroll
      for (int ni = 0; ni < 4; ++ni)
        acc[ni][tt] = acc[ni][tt] + ev * w64c[ni] + b3c[ni];
    }
    __syncthreads();
#pragma unroll
    for (int ni = 0; ni < 4; ++ni) {
      int cc = ni * 16 + r;
#pragma unroll
      for (int tt = 0; tt < 4; ++tt) {
        int jj = w * 16 + q * 4 + tt;
        A[cc * 136 + jj] = f2bf(acc[ni][tt]);
      }
    }
    __syncthreads();
    {
      int pl = t >> 3, off = (t & 7) * 8;
#pragma unroll
      for (int k = 0; k < 2; ++k) {
        int plane = k * 32 + pl;
        uint4 v = *(const uint4*)&A[plane * 136 + off];
        *(uint4*)(PT + (size_t)plane * 1048576 + (size_t)i * 1024 + j0 + off) = v;
      }
    }
  }
}

// ---------------- graph-norm stats, pass 1: coalesced partial sums ----------
__global__ void k_stats(const u16* __restrict__ Tg, float* __restrict__ S,
                        float* __restrict__ SS) {
  int b = blockIdx.x;  // grid 512 = 64 c x 8 i-chunks
  int c = b >> 3, ic = b & 7;
  int t = threadIdx.x;
  const u16* base = Tg + (size_t)c * 1048576 + (size_t)ic * 131072 + t * 4;
  float s0 = 0.f, s1 = 0.f, s2 = 0.f, s3 = 0.f;
  float q0 = 0.f, q1 = 0.f, q2 = 0.f, q3 = 0.f;
  for (int ii = 0; ii < 128; ++ii) {
    uint2 u = *(const uint2*)(base + (size_t)ii * 1024);
    float v0 = bf2f((u16)(u.x & 0xffffu)), v1 = bf2f((u16)(u.x >> 16));
    float v2 = bf2f((u16)(u.y & 0xffffu)), v3 = bf2f((u16)(u.y >> 16));
    s0 += v0; q0 += v0 * v0;
    s1 += v1; q1 += v1 * v1;
    s2 += v2; q2 += v2 * v2;
    s3 += v3; q3 += v3 * v3;
  }
  int base2 = c * 1024 + t * 4;
  atomicAdd(&S[base2 + 0], s0);
  atomicAdd(&S[base2 + 1], s1);
  atomicAdd(&S[base2 + 2], s2);
  atomicAdd(&S[base2 + 3], s3);
  atomicAdd(&SS[base2 + 0], q0);
  atomicAdd(&SS[base2 + 1], q1);
  atomicAdd(&SS[base2 + 2], q2);
  atomicAdd(&SS[base2 + 3], q3);
}

// ---------------- graph-norm stats, pass 2: finalize ----------
__global__ void k_statsfin(const float* __restrict__ S, const float* __restrict__ SS,
                           const float* __restrict__ gn3w, const float* __restrict__ gn3b,
                           const float* __restrict__ gn3a,
                           float* __restrict__ normA, float* __restrict__ normB) {
  int idx = blockIdx.x * 256 + threadIdx.x;  // grid 256 -> 65536 = j*64+c
  int c = idx & 63, j = idx >> 6;
  float sum = S[c * 1024 + j];
  float ssum = SS[c * 1024 + j];
  float m = sum * (1.f / 1024.f);
  float a = gn3a[c];
  float var = ssum * (1.f / 1024.f) - (2.f * a - a * a) * m * m;
  float sc = gn3w[c] * rsqrtf(fmaxf(var, 0.f) + 1e-5f);
  normA[idx] = sc;
  normB[idx] = gn3b[c] - sc * a * m;
}

// ---------------- gather + symmetric product + final dot ----------------
__global__ void k_final(const u16* __restrict__ Tg, const float* __restrict__ normA,
                        const float* __restrict__ normB, const int* __restrict__ pos,
                        const float* __restrict__ ldW, const float* __restrict__ ldb,
                        float* __restrict__ out) {
  int t = threadIdx.x, w = t >> 6, lane = t & 63;  // grid 2048 x 256, wave/pos
  int p = blockIdx.x * 4 + w;
  int i = pos[2 * p], j = pos[2 * p + 1];
  float t1 = bf2f(Tg[(size_t)lane * 1048576 + (size_t)i * 1024 + j]);
  float y1 = fmaxf(normA[j * 64 + lane] * t1 + normB[j * 64 + lane], 0.f);
  float t2 = bf2f(Tg[(size_t)lane * 1048576 + (size_t)j * 1024 + i]);
  float y2 = fmaxf(normA[i * 64 + lane] * t2 + normB[i * 64 + lane], 0.f);
  float z = y1 * y2 * ldW[lane];
#pragma unroll
  for (int off = 32; off > 0; off >>= 1) z += __shfl_down(z, off, 64);
  if (lane == 0) out[p] = z + ldb[0];
}

extern "C" void kernel_launch(void* const* d_in, const int* in_sizes, int n_in,
                              void* d_out, int out_size, void* d_ws, size_t ws_size,
                              hipStream_t stream) {
  const int* xids   = (const int*)d_in[0];
  const int* ei     = (const int*)d_in[1];
  const int* pos    = (const int*)d_in[2];
  const float* emb  = (const float*)d_in[3];
  const float* gW0  = (const float*)d_in[4];
  const float* gb0  = (const float*)d_in[5];
  const float* gnw0 = (const float*)d_in[6];
  const float* gnb0 = (const float*)d_in[7];
  const float* gna0 = (const float*)d_in[8];
  const float* gW1  = (const float*)d_in[9];
  const float* gb1  = (const float*)d_in[10];
  const float* gnw1 = (const float*)d_in[11];
  const float* gnb1 = (const float*)d_in[12];
  const float* gna1 = (const float*)d_in[13];
  const float* m1W  = (const float*)d_in[14];
  const float* m1b  = (const float*)d_in[15];
  const float* m2W  = (const float*)d_in[16];
  const float* m2b  = (const float*)d_in[17];
  const float* m3W  = (const float*)d_in[18];
  const float* m3b  = (const float*)d_in[19];
  const float* gn3w = (const float*)d_in[20];
  const float* gn3b = (const float*)d_in[21];
  const float* gn3a = (const float*)d_in[22];
  const float* ldW  = (const float*)d_in[23];
  const float* ldb  = (const float*)d_in[24];

  char* ws = (char*)d_ws;
  float* xf   = (float*)(ws + 0);
  float* h    = (float*)(ws + 262144);
  float* agg  = (float*)(ws + 524288);
  float* deg  = (float*)(ws + 786432);
  u16*   xb   = (u16*)(ws + 790528);
  unsigned char* eim = (unsigned char*)(ws + 921600);
  float* normA = (float*)(ws + 1970176);
  float* normB = (float*)(ws + 2232320);
  u16* x1tg = (u16*)(ws + 2494464);
  u16* x2tg = (u16*)(ws + 36048896);
  u16* prod = (u16*)(ws + 69603328);  // later overwritten in place by T
  float* Sp  = (float*)x1tg;          // stats partials overlay dead x1tg
  float* SSp = Sp + 65536;
  float* out = (float*)d_out;

  k_setup<<<1024, 256, 0, stream>>>(xids, emb, xf, deg, (u32*)eim);
  k_edges<<<64, 256, 0, stream>>>(ei, deg, eim);
  // GCN layer 0
  k_gemm_node<<<1024, 64, 0, stream>>>(xf, gW0, gb0, deg, h, agg);
  k_agg<<<4096, 256, 0, stream>>>(ei, deg, h, agg);
  k_gnorm<<<64, 256, 0, stream>>>(agg, gnw0, gnb0, gna0, xf, xb, 0);
  // GCN layer 1
  k_gemm_node<<<1024, 64, 0, stream>>>(xf, gW1, gb1, deg, h, agg);
  k_agg<<<4096, 256, 0, stream>>>(ei, deg, h, agg);
  k_gnorm<<<64, 256, 0, stream>>>(agg, gnw1, gnb1, gna1, xf, xb, 1);
  // pairwise maps + batched 1024^3 GEMM, 4 channel-groups of 16
  for (int g = 0; g < 4; ++g) {
    k_build12<<<512, 256, 0, stream>>>(xb, eim, m1W, m1b, m2W, m2b, x1tg, x2tg, g * 16);
    k_prodgemm<<<1024, 256, 0, stream>>>(x1tg, x2tg, prod, g * 16);
  }
  // T tensor (in place over prod) + stats + final
  k_buildT<<<1024, 256, 0, stream>>>(xb, eim, prod, m3W, m3b, Sp, SSp);
  k_stats<<<512, 256, 0, stream>>>(prod, Sp, SSp);
  k_statsfin<<<256, 256, 0, stream>>>(Sp, SSp, gn3w, gn3b, gn3a, normA, normB);
  k_final<<<2048, 256, 0, stream>>>(prod, normA, normB, pos, ldW, ldb, out);
}

// Round 11
// 517.300 us; speedup vs baseline: 1.0666x; 1.0666x over previous
//
#include <hip/hip_runtime.h>

// FWLNet pipeline; see R5-R10 notes.
//
// R11 (from R10 FAIL @551.7us, R9 baseline 520.6us):
//  - k_buildT: REVERTED to R9 (R10's 4-blocks/CU raised in-flight working set
//    past L3 residency: FETCH 67->144MB, dur 79->108us. Occupancy was not the
//    limiter; L3 reuse was).
//  - k_prodgemm: XCD-aware swizzle: cl=(b&7)+8*(b>>9), tile=(b>>3)&63 ->
//    all 64 tiles of one channel on one XCD consecutively; per-XCD A+B
//    working set = 4MB = L2 capacity (was: all 16 channels -> L3-served).
//
// ws layout unchanged (~194.4 MB).

typedef unsigned short u16;
typedef unsigned int u32;

#define DI static __device__ __forceinline__

DI float bf2f(u16 u) { union { u32 i; float f; } v; v.i = ((u32)u) << 16; return v.f; }
DI u16 f2bf(float f) {
  union { float f; u32 i; } v; v.f = f;
  u32 u = v.i;
  return (u16)((u + 0x7fffu + ((u >> 16) & 1u)) >> 16);
}

typedef __bf16 bf16x8 __attribute__((ext_vector_type(8)));
typedef float f32x4 __attribute__((ext_vector_type(4)));

#define MFMA16(a, b, c) __builtin_amdgcn_mfma_f32_16x16x32_bf16((a), (b), (c), 0, 0, 0)

typedef const __attribute__((address_space(1))) u32* gas1;
typedef __attribute__((address_space(3))) u32* las3;

// ---------------- node pipeline ----------------

__global__ void k_setup(const int* __restrict__ xids, const float* __restrict__ emb,
                        float* __restrict__ xf, float* __restrict__ deg,
                        u32* __restrict__ eimu) {
  int g = blockIdx.x * 256 + threadIdx.x;  // grid 1024
  if (g < 262144) eimu[g] = 0u;
  if (g < 1024) deg[g] = 1.0f;  // self-loop
  if (g < 65536) {
    int i = g >> 6, d = g & 63;
    xf[g] = emb[xids[i] * 64 + d];
  }
}

__global__ void k_edges(const int* __restrict__ ei, float* __restrict__ deg,
                        unsigned char* __restrict__ eim) {
  int e = blockIdx.x * 256 + threadIdx.x;  // grid 64
  if (e < 16384) {
    int s = ei[e], d = ei[16384 + e];
    atomicAdd(&deg[d], 1.0f);
    eim[s * 1024 + d] = 1;
  }
}

__global__ void k_gemm_node(const float* __restrict__ xf, const float* __restrict__ W,
                            const float* __restrict__ gb, const float* __restrict__ deg,
                            float* __restrict__ h, float* __restrict__ agg) {
  __shared__ float xrow[64];
  int i = blockIdx.x, c = threadIdx.x;  // grid 1024 x 64
  xrow[c] = xf[i * 64 + c];
  __syncthreads();
  float s = 0.f;
#pragma unroll
  for (int d = 0; d < 64; ++d) s += xrow[d] * W[d * 64 + c];
  h[i * 64 + c] = s;
  agg[i * 64 + c] = s / deg[i] + gb[c];
}

__global__ void k_agg(const int* __restrict__ ei, const float* __restrict__ deg,
                      const float* __restrict__ h, float* __restrict__ agg) {
  int g = blockIdx.x * 256 + threadIdx.x;  // grid 4096 -> e x c
  int e = g >> 6, c = g & 63;
  int s = ei[e], d = ei[16384 + e];
  float nrm = rsqrtf(deg[s]) * rsqrtf(deg[d]);
  atomicAdd(&agg[d * 64 + c], nrm * h[s * 64 + c]);
}

__global__ void k_gnorm(const float* __restrict__ agg, const float* __restrict__ gw,
                        const float* __restrict__ gbb, const float* __restrict__ ga,
                        float* __restrict__ xf, u16* __restrict__ xb, int last) {
  int c = blockIdx.x, t = threadIdx.x;  // grid 64 x 256
  float s = 0.f, ss = 0.f;
  for (int i = t; i < 1024; i += 256) {
    float v = agg[i * 64 + c];
    s += v; ss += v * v;
  }
  __shared__ float Ls[256], Lss[256];
  Ls[t] = s; Lss[t] = ss;
  __syncthreads();
  for (int off = 128; off > 0; off >>= 1) {
    if (t < off) { Ls[t] += Ls[t + off]; Lss[t] += Lss[t + off]; }
    __syncthreads();
  }
  float m = Ls[0] * (1.f / 1024.f);
  float a = ga[c];
  float var = Lss[0] * (1.f / 1024.f) - (2.f * a - a * a) * m * m;
  float sc = gw[c] * rsqrtf(fmaxf(var, 0.f) + 1e-5f);
  float bb = gbb[c];
  for (int i = t; i < 1024; i += 256) {
    float v = agg[i * 64 + c];
    float y = fmaxf(sc * (v - a * m) + bb, 0.f);
    xf[i * 64 + c] = y;
    if (last) xb[i * 64 + c] = f2bf(y);
  }
}

// ---------------- x1t / x2T builder: 4 channels per block ----------------
__global__ __launch_bounds__(256, 2) void k_build12(
    const u16* __restrict__ xbg, const unsigned char* __restrict__ eim,
    const float* __restrict__ m1W, const float* __restrict__ m1b,
    const float* __restrict__ m2W, const float* __restrict__ m2b,
    u16* __restrict__ x1tg, u16* __restrict__ x2tg, int cbase) {
  __shared__ u16 As[128 * 80];
  __shared__ u16 Bs[128 * 80];
  __shared__ u16 Cs[64 * 140];
  __shared__ unsigned char El[128 * 132];
  __shared__ float wsc[64];
  int b = blockIdx.x;  // grid 512 = 2(which) x 64 tiles x 4 channel-quads
  int cg = b & 3;
  int rest = b >> 2;
  int which = rest >> 6;
  int t6 = rest & 63;
  int rbase = (t6 >> 3) * 128, sbase = (t6 & 7) * 128;
  const float* W = which ? m2W : m1W;
  const float* bias = which ? m2b : m1b;
  u16* outg = which ? x2tg : x1tg;
  int t = threadIdx.x;
  {
    int row = t >> 1, half = t & 1;
    const u32* gB = (const u32*)(xbg + (sbase + row) * 64 + half * 32);
    u32* dstB = (u32*)&Bs[row * 80 + half * 32];
#pragma unroll
    for (int k = 0; k < 16; ++k) dstB[k] = gB[k];
    int ab = which ? sbase : rbase;
    int bb = which ? rbase : sbase;
    const u32* gE = (const u32*)(eim + (size_t)(ab + row) * 1024 + bb + half * 64);
    u32* dstE = (u32*)&El[row * 132 + half * 64];
#pragma unroll
    for (int k = 0; k < 16; ++k) dstE[k] = gE[k];
  }
  int lane = t & 63, w = t >> 6;
  int q = lane >> 4, r = lane & 15;
  int wr = w >> 1, wc = w & 1;
  for (int ci = 0; ci < 4; ++ci) {
    int cl = cg * 4 + ci;
    int c = cbase + cl;
    if (t < 64) wsc[t] = W[t * 64 + c];
    __syncthreads();
    {
      int row = t >> 1, half = t & 1;
      const u32* ga = (const u32*)(xbg + (rbase + row) * 64 + half * 32);
      u32* dstA = (u32*)&As[row * 80 + half * 32];
#pragma unroll
      for (int k = 0; k < 16; ++k) {
        u32 u = ga[k];
        float f0 = bf2f((u16)(u & 0xffffu)) * wsc[half * 32 + 2 * k];
        float f1 = bf2f((u16)(u >> 16)) * wsc[half * 32 + 2 * k + 1];
        dstA[k] = (u32)f2bf(f0) | ((u32)f2bf(f1) << 16);
      }
    }
    __syncthreads();
    f32x4 z4 = {0.f, 0.f, 0.f, 0.f};
    f32x4 acc[4][4];
#pragma unroll
    for (int mi = 0; mi < 4; ++mi)
#pragma unroll
      for (int ni = 0; ni < 4; ++ni) acc[mi][ni] = z4;
#pragma unroll
    for (int ks = 0; ks < 2; ++ks) {
      bf16x8 af[4], bfr[4];
#pragma unroll
      for (int mi = 0; mi < 4; ++mi)
        af[mi] = *(const bf16x8*)&As[(wr * 64 + mi * 16 + r) * 80 + ks * 32 + q * 8];
#pragma unroll
      for (int ni = 0; ni < 4; ++ni)
        bfr[ni] = *(const bf16x8*)&Bs[(wc * 64 + ni * 16 + r) * 80 + ks * 32 + q * 8];
#pragma unroll
      for (int mi = 0; mi < 4; ++mi)
#pragma unroll
        for (int ni = 0; ni < 4; ++ni) acc[mi][ni] = MFMA16(af[mi], bfr[ni], acc[mi][ni]);
    }
    float w64 = W[64 * 64 + c];
    float bsv = bias[c];
#pragma unroll
    for (int mi = 0; mi < 4; ++mi) {
#pragma unroll
      for (int ni = 0; ni < 4; ++ni) {
        int col = wc * 64 + ni * 16 + r;
#pragma unroll
        for (int tt = 0; tt < 4; ++tt) {
          int row2 = wr * 64 + mi * 16 + q * 4 + tt;
          float e = (float)(which ? El[col * 132 + row2] : El[row2 * 132 + col]);
          acc[mi][ni][tt] = fmaxf(acc[mi][ni][tt] + e * w64 + bsv, 0.f);
        }
      }
    }
    u16* outp = outg + (size_t)cl * 1048576;
#pragma unroll
    for (int p = 0; p < 2; ++p) {
      __syncthreads();
      if (wr == p) {
#pragma unroll
        for (int mi = 0; mi < 4; ++mi)
#pragma unroll
          for (int ni = 0; ni < 4; ++ni) {
            int col = wc * 64 + ni * 16 + r;
#pragma unroll
            for (int tt = 0; tt < 4; ++tt) {
              int lrow = mi * 16 + q * 4 + tt;
              Cs[lrow * 140 + col] = f2bf(acc[mi][ni][tt]);
            }
          }
      }
      __syncthreads();
      {
        int rl = t >> 4, ch = t & 15;
#pragma unroll
        for (int it = 0; it < 4; ++it) {
          int row = it * 16 + rl;
          uint4 v = *(const uint4*)&Cs[row * 140 + ch * 8];
          *(uint4*)(outp + (size_t)(rbase + p * 64 + row) * 1024 + sbase + ch * 8) = v;
        }
      }
    }
  }
}

// ---------------- batched prod GEMM (16 channels per launch) ----------------
// R11: XCD-aware block swizzle — all 64 tiles of one channel land on one XCD
// consecutively (blockIdx%8 round-robin heuristic): per-XCD A+B = 4MB = L2.
__global__ __launch_bounds__(256, 4) void k_prodgemm(
    const u16* __restrict__ x1tg, const u16* __restrict__ x2tg,
    u16* __restrict__ prod, int cbase) {
  __shared__ u16 pool[17408];
  int b = blockIdx.x;  // grid 1024
  int cl = (b & 7) + ((b >> 9) << 3);   // channel: XCD x gets cl=x then cl=x+8
  int tile = (b >> 3) & 63;             // 64 tiles of that channel, in order
  int i0 = (tile >> 3) * 128, j0 = (tile & 7) * 128;
  const u16* Ap = x1tg + (size_t)cl * 1048576;
  const u16* Bp = x2tg + (size_t)cl * 1048576;
  u16* Pp = prod + (size_t)(cbase + cl) * 1048576;
  int t = threadIdx.x, lane = t & 63, w = t >> 6;
  int q = lane >> 4, r = lane & 15;
  int wr = w >> 1, wc = w & 1;
  int lrow = lane >> 3, lcol = (lane & 7) * 8;
  f32x4 z4 = {0.f, 0.f, 0.f, 0.f};
  f32x4 acc[4][4];
#pragma unroll
  for (int mi = 0; mi < 4; ++mi)
#pragma unroll
    for (int ni = 0; ni < 4; ++ni) acc[mi][ni] = z4;
  for (int kk = 0; kk < 1024; kk += 64) {
    __syncthreads();
#pragma unroll
    for (int s8 = 0; s8 < 4; ++s8) {
      int rowbase = w * 32 + s8 * 8;
      int grow = rowbase + lrow;
      __builtin_amdgcn_global_load_lds(
          (gas1)(Ap + (size_t)(i0 + grow) * 1024 + kk + lcol),
          (las3)&pool[rowbase * 64], 16, 0, 0);
      __builtin_amdgcn_global_load_lds(
          (gas1)(Bp + (size_t)(j0 + grow) * 1024 + kk + lcol),
          (las3)&pool[8192 + rowbase * 64], 16, 0, 0);
    }
    __syncthreads();
#pragma unroll
    for (int ks = 0; ks < 2; ++ks) {
      bf16x8 af[4], bfr[4];
#pragma unroll
      for (int mi = 0; mi < 4; ++mi)
        af[mi] = *(const bf16x8*)&pool[(wr * 64 + mi * 16 + r) * 64 + ks * 32 + q * 8];
#pragma unroll
      for (int ni = 0; ni < 4; ++ni)
        bfr[ni] = *(const bf16x8*)&pool[8192 + (wc * 64 + ni * 16 + r) * 64 + ks * 32 + q * 8];
#pragma unroll
      for (int mi = 0; mi < 4; ++mi)
#pragma unroll
        for (int ni = 0; ni < 4; ++ni) acc[mi][ni] = MFMA16(af[mi], bfr[ni], acc[mi][ni]);
    }
  }
  __syncthreads();
#pragma unroll
  for (int mi = 0; mi < 4; ++mi)
#pragma unroll
    for (int ni = 0; ni < 4; ++ni) {
      int col = wc * 64 + ni * 16 + r;
#pragma unroll
      for (int tt = 0; tt < 4; ++tt) {
        int row2 = wr * 64 + mi * 16 + q * 4 + tt;
        pool[row2 * 136 + col] = f2bf(acc[mi][ni][tt]);
      }
    }
  __syncthreads();
  {
    int rseg = t >> 4, cseg = t & 15;
#pragma unroll
    for (int it = 0; it < 8; ++it) {
      int row = it * 16 + rseg;
      uint4 v = *(const uint4*)&pool[row * 136 + cseg * 8];
      *(uint4*)(Pp + (size_t)(i0 + row) * 1024 + j0 + cseg * 8) = v;
    }
  }
}

// ---------------- T = [x_i*x_j | eim | prod] @ m3W + b3 (IN PLACE over prod) --
// R9 version (reverted from R10): 64-j chunks, LDS 43.5KB, 3 blocks/CU.
__global__ __launch_bounds__(256, 3) void k_buildT(
    const u16* __restrict__ xbg, const unsigned char* __restrict__ eim,
    u16* PT, const float* __restrict__ m3W, const float* __restrict__ m3b,
    float* __restrict__ S, float* __restrict__ SS) {
  __shared__ u16 A[64 * 136];
  __shared__ u16 Wt[64 * 136];
  __shared__ u16 scratch[64 * 66];
  __shared__ float xi[64];
  int i = blockIdx.x;  // grid 1024
  int t = threadIdx.x, lane = t & 63, w = t >> 6;
  int q = lane >> 4, r = lane & 15;
  {
    int zidx = i * 256 + t;
    if (zidx < 65536) { S[zidx] = 0.f; SS[zidx] = 0.f; }
  }
  if (t < 64) xi[t] = bf2f(xbg[i * 64 + t]);
  {
    int row = t >> 1, half = t & 1;
    int rsrc = row < 64 ? row : row + 1;  // skip eim row 64
    const float4* gw = (const float4*)(m3W + rsrc * 64 + half * 32);
#pragma unroll
    for (int k = 0; k < 8; ++k) {
      float4 f = gw[k];
      Wt[(half * 32 + 4 * k + 0) * 136 + row] = f2bf(f.x);
      Wt[(half * 32 + 4 * k + 1) * 136 + row] = f2bf(f.y);
      Wt[(half * 32 + 4 * k + 2) * 136 + row] = f2bf(f.z);
      Wt[(half * 32 + 4 * k + 3) * 136 + row] = f2bf(f.w);
    }
  }
  float w64c[4], b3c[4];
#pragma unroll
  for (int ni = 0; ni < 4; ++ni) {
    int cc = ni * 16 + r;
    w64c[ni] = m3W[64 * 64 + cc];
    b3c[ni] = m3b[cc];
  }
  for (int jc = 0; jc < 16; ++jc) {
    int j0 = jc * 64;
    __syncthreads();
    {
      int jj = t >> 2, quar = t & 3;
      const u32* gx = (const u32*)(xbg + (j0 + jj) * 64 + quar * 16);
      u32* dst = (u32*)&A[jj * 136 + quar * 16];
#pragma unroll
      for (int k = 0; k < 8; ++k) {
        u32 u = gx[k];
        float f0 = bf2f((u16)(u & 0xffffu)) * xi[quar * 16 + 2 * k];
        float f1 = bf2f((u16)(u >> 16)) * xi[quar * 16 + 2 * k + 1];
        dst[k] = (u32)f2bf(f0) | ((u32)f2bf(f1) << 16);
      }
      int p = t >> 2, pt = t & 3;
      const uint4* gp = (const uint4*)(PT + (size_t)p * 1048576 + (size_t)i * 1024 + j0 + pt * 16);
      uint4 v0 = gp[0];
      uint2 v1 = ((const uint2*)gp)[2];
      uint2 v2 = ((const uint2*)gp)[3];
      u32* sw = (u32*)&scratch[p * 66 + pt * 16];
      sw[0] = v0.x; sw[1] = v0.y; sw[2] = v0.z; sw[3] = v0.w;
      sw[4] = v1.x; sw[5] = v1.y; sw[6] = v2.x; sw[7] = v2.y;
    }
    __syncthreads();
    {
#pragma unroll
      for (int jj2 = 0; jj2 < 8; ++jj2) {
        int jr = w * 16 + jj2 * 2;
        u32 two = *(const u32*)&scratch[lane * 66 + jr];
        A[jr * 136 + 64 + lane] = (u16)(two & 0xffffu);
        A[(jr + 1) * 136 + 64 + lane] = (u16)(two >> 16);
      }
    }
    __syncthreads();
    f32x4 z4 = {0.f, 0.f, 0.f, 0.f};
    f32x4 acc[4];
#pragma unroll
    for (int ni = 0; ni < 4; ++ni) acc[ni] = z4;
#pragma unroll
    for (int ks = 0; ks < 4; ++ks) {
      bf16x8 af, bfr[4];
      af = *(const bf16x8*)&A[(w * 16 + r) * 136 + ks * 32 + q * 8];
#pragma unroll
      for (int ni = 0; ni < 4; ++ni)
        bfr[ni] = *(const bf16x8*)&Wt[(ni * 16 + r) * 136 + ks * 32 + q * 8];
#pragma unroll
      for (int ni = 0; ni < 4; ++ni) acc[ni] = MFMA16(af, bfr[ni], acc[ni]);
    }
#pragma unroll
    for (int tt = 0; tt < 4; ++tt) {
      int jj = w * 16 + q * 4 + tt;
      float ev = (float)eim[(size_t)i * 1024 + j0 + jj];
#pragma unroll
      for (int ni = 0; ni < 4; ++ni)
        acc[ni][tt] = acc[ni][tt] + ev * w64c[ni] + b3c[ni];
    }
    __syncthreads();
#pragma unroll
    for (int ni = 0; ni < 4; ++ni) {
      int cc = ni * 16 + r;
#pragma unroll
      for (int tt = 0; tt < 4; ++tt) {
        int jj = w * 16 + q * 4 + tt;
        A[cc * 136 + jj] = f2bf(acc[ni][tt]);
      }
    }
    __syncthreads();
    {
      int pl = t >> 3, off = (t & 7) * 8;
#pragma unroll
      for (int k = 0; k < 2; ++k) {
        int plane = k * 32 + pl;
        uint4 v = *(const uint4*)&A[plane * 136 + off];
        *(uint4*)(PT + (size_t)plane * 1048576 + (size_t)i * 1024 + j0 + off) = v;
      }
    }
  }
}

// ---------------- graph-norm stats, pass 1: coalesced partial sums ----------
__global__ void k_stats(const u16* __restrict__ Tg, float* __restrict__ S,
                        float* __restrict__ SS) {
  int b = blockIdx.x;  // grid 512 = 64 c x 8 i-chunks
  int c = b >> 3, ic = b & 7;
  int t = threadIdx.x;
  const u16* base = Tg + (size_t)c * 1048576 + (size_t)ic * 131072 + t * 4;
  float s0 = 0.f, s1 = 0.f, s2 = 0.f, s3 = 0.f;
  float q0 = 0.f, q1 = 0.f, q2 = 0.f, q3 = 0.f;
  for (int ii = 0; ii < 128; ++ii) {
    uint2 u = *(const uint2*)(base + (size_t)ii * 1024);
    float v0 = bf2f((u16)(u.x & 0xffffu)), v1 = bf2f((u16)(u.x >> 16));
    float v2 = bf2f((u16)(u.y & 0xffffu)), v3 = bf2f((u16)(u.y >> 16));
    s0 += v0; q0 += v0 * v0;
    s1 += v1; q1 += v1 * v1;
    s2 += v2; q2 += v2 * v2;
    s3 += v3; q3 += v3 * v3;
  }
  int base2 = c * 1024 + t * 4;
  atomicAdd(&S[base2 + 0], s0);
  atomicAdd(&S[base2 + 1], s1);
  atomicAdd(&S[base2 + 2], s2);
  atomicAdd(&S[base2 + 3], s3);
  atomicAdd(&SS[base2 + 0], q0);
  atomicAdd(&SS[base2 + 1], q1);
  atomicAdd(&SS[base2 + 2], q2);
  atomicAdd(&SS[base2 + 3], q3);
}

// ---------------- graph-norm stats, pass 2: finalize ----------
__global__ void k_statsfin(const float* __restrict__ S, const float* __restrict__ SS,
                           const float* __restrict__ gn3w, const float* __restrict__ gn3b,
                           const float* __restrict__ gn3a,
                           float* __restrict__ normA, float* __restrict__ normB) {
  int idx = blockIdx.x * 256 + threadIdx.x;  // grid 256 -> 65536 = j*64+c
  int c = idx & 63, j = idx >> 6;
  float sum = S[c * 1024 + j];
  float ssum = SS[c * 1024 + j];
  float m = sum * (1.f / 1024.f);
  float a = gn3a[c];
  float var = ssum * (1.f / 1024.f) - (2.f * a - a * a) * m * m;
  float sc = gn3w[c] * rsqrtf(fmaxf(var, 0.f) + 1e-5f);
  normA[idx] = sc;
  normB[idx] = gn3b[c] - sc * a * m;
}

// ---------------- gather + symmetric product + final dot ----------------
__global__ void k_final(const u16* __restrict__ Tg, const float* __restrict__ normA,
                        const float* __restrict__ normB, const int* __restrict__ pos,
                        const float* __restrict__ ldW, const float* __restrict__ ldb,
                        float* __restrict__ out) {
  int t = threadIdx.x, w = t >> 6, lane = t & 63;  // grid 2048 x 256, wave/pos
  int p = blockIdx.x * 4 + w;
  int i = pos[2 * p], j = pos[2 * p + 1];
  float t1 = bf2f(Tg[(size_t)lane * 1048576 + (size_t)i * 1024 + j]);
  float y1 = fmaxf(normA[j * 64 + lane] * t1 + normB[j * 64 + lane], 0.f);
  float t2 = bf2f(Tg[(size_t)lane * 1048576 + (size_t)j * 1024 + i]);
  float y2 = fmaxf(normA[i * 64 + lane] * t2 + normB[i * 64 + lane], 0.f);
  float z = y1 * y2 * ldW[lane];
#pragma unroll
  for (int off = 32; off > 0; off >>= 1) z += __shfl_down(z, off, 64);
  if (lane == 0) out[p] = z + ldb[0];
}

extern "C" void kernel_launch(void* const* d_in, const int* in_sizes, int n_in,
                              void* d_out, int out_size, void* d_ws, size_t ws_size,
                              hipStream_t stream) {
  const int* xids   = (const int*)d_in[0];
  const int* ei     = (const int*)d_in[1];
  const int* pos    = (const int*)d_in[2];
  const float* emb  = (const float*)d_in[3];
  const float* gW0  = (const float*)d_in[4];
  const float* gb0  = (const float*)d_in[5];
  const float* gnw0 = (const float*)d_in[6];
  const float* gnb0 = (const float*)d_in[7];
  const float* gna0 = (const float*)d_in[8];
  const float* gW1  = (const float*)d_in[9];
  const float* gb1  = (const float*)d_in[10];
  const float* gnw1 = (const float*)d_in[11];
  const float* gnb1 = (const float*)d_in[12];
  const float* gna1 = (const float*)d_in[13];
  const float* m1W  = (const float*)d_in[14];
  const float* m1b  = (const float*)d_in[15];
  const float* m2W  = (const float*)d_in[16];
  const float* m2b  = (const float*)d_in[17];
  const float* m3W  = (const float*)d_in[18];
  const float* m3b  = (const float*)d_in[19];
  const float* gn3w = (const float*)d_in[20];
  const float* gn3b = (const float*)d_in[21];
  const float* gn3a = (const float*)d_in[22];
  const float* ldW  = (const float*)d_in[23];
  const float* ldb  = (const float*)d_in[24];

  char* ws = (char*)d_ws;
  float* xf   = (float*)(ws + 0);
  float* h    = (float*)(ws + 262144);
  float* agg  = (float*)(ws + 524288);
  float* deg  = (float*)(ws + 786432);
  u16*   xb   = (u16*)(ws + 790528);
  unsigned char* eim = (unsigned char*)(ws + 921600);
  float* normA = (float*)(ws + 1970176);
  float* normB = (float*)(ws + 2232320);
  u16* x1tg = (u16*)(ws + 2494464);
  u16* x2tg = (u16*)(ws + 36048896);
  u16* prod = (u16*)(ws + 69603328);  // later overwritten in place by T
  float* Sp  = (float*)x1tg;          // stats partials overlay dead x1tg
  float* SSp = Sp + 65536;
  float* out = (float*)d_out;

  k_setup<<<1024, 256, 0, stream>>>(xids, emb, xf, deg, (u32*)eim);
  k_edges<<<64, 256, 0, stream>>>(ei, deg, eim);
  // GCN layer 0
  k_gemm_node<<<1024, 64, 0, stream>>>(xf, gW0, gb0, deg, h, agg);
  k_agg<<<4096, 256, 0, stream>>>(ei, deg, h, agg);
  k_gnorm<<<64, 256, 0, stream>>>(agg, gnw0, gnb0, gna0, xf, xb, 0);
  // GCN layer 1
  k_gemm_node<<<1024, 64, 0, stream>>>(xf, gW1, gb1, deg, h, agg);
  k_agg<<<4096, 256, 0, stream>>>(ei, deg, h, agg);
  k_gnorm<<<64, 256, 0, stream>>>(agg, gnw1, gnb1, gna1, xf, xb, 1);
  // pairwise maps + batched 1024^3 GEMM, 4 channel-groups of 16
  for (int g = 0; g < 4; ++g) {
    k_build12<<<512, 256, 0, stream>>>(xb, eim, m1W, m1b, m2W, m2b, x1tg, x2tg, g * 16);
    k_prodgemm<<<1024, 256, 0, stream>>>(x1tg, x2tg, prod, g * 16);
  }
  // T tensor (in place over prod) + stats + final
  k_buildT<<<1024, 256, 0, stream>>>(xb, eim, prod, m3W, m3b, Sp, SSp);
  k_stats<<<512, 256, 0, stream>>>(prod, Sp, SSp);
  k_statsfin<<<256, 256, 0, stream>>>(Sp, SSp, gn3w, gn3b, gn3a, normA, normB);
  k_final<<<2048, 256, 0, stream>>>(prod, normA, normB, pos, ldW, ldb, out);
}